// Round 1
// baseline (4606.978 us; speedup 1.0000x reference)
//
#include <hip/hip_runtime.h>
#include <stdint.h>

#define B_   2
#define L_   1024
#define D_   1024
#define NL_  4
#define V_   50280
#define DI_  2048
#define DS_  16
#define DC_  4
#define DTR_ 64

typedef __attribute__((ext_vector_type(8))) short bf16x8_t;   // 8 bf16 in 4 VGPRs
typedef __attribute__((ext_vector_type(4))) float f32x4_t;

__device__ __forceinline__ unsigned short f2bf(float f) {
  union { float f; unsigned u; } x; x.f = f;
  unsigned r = x.u + 0x7fffu + ((x.u >> 16) & 1u);   // RTNE
  return (unsigned short)(r >> 16);
}

__device__ __forceinline__ void gload_lds16(const void* g, const void* l) {
  __builtin_amdgcn_global_load_lds(
      (const __attribute__((address_space(1))) void*)(uintptr_t)g,
      (__attribute__((address_space(3))) void*)(unsigned int)(uintptr_t)l,
      16, 0, 0);
}

// ---------------- bf16 GEMM: C(f32, MxN) = A(MxK,bf16,lda) * B^T (B is NxK bf16) ----
// m97 structure: 128x128 tile, BK=32, 4 waves (2x2 of 64x64), global_load_lds w=16.
__global__ __launch_bounds__(256) void gemm_bt(
    const unsigned short* __restrict__ A,
    const unsigned short* __restrict__ Bw,
    float* __restrict__ C,
    int N, int K, int lda)
{
  __shared__ unsigned short sA[128 * 32];
  __shared__ unsigned short sB[128 * 32];
  const int t    = threadIdx.x;
  const int lane = t & 63;
  const int w    = t >> 6;
  const int wm   = w >> 1;        // 2 waves along M
  const int wn   = w & 1;         // 2 waves along N
  const int m0   = blockIdx.y * 128;
  const int n0   = blockIdx.x * 128;

  f32x4_t acc[4][4] = {};

  const int srow = t >> 2;        // 0..63, staging row
  const int scol = (t & 3) * 8;   // bf16 offset within 32-elem row
  const int lr   = lane & 15;
  const int kg   = lane >> 4;

  int br0 = n0 + srow;       if (br0 > N - 1) br0 = N - 1;   // N-tail clamp
  int br1 = n0 + srow + 64;  if (br1 > N - 1) br1 = N - 1;
  const unsigned short* gA0 = A  + (size_t)(m0 + srow) * lda + scol;
  const unsigned short* gA1 = gA0 + (size_t)64 * lda;
  const unsigned short* gB0 = Bw + (size_t)br0 * K + scol;
  const unsigned short* gB1 = Bw + (size_t)br1 * K + scol;

  for (int k0 = 0; k0 < K; k0 += 32) {
    gload_lds16(gA0 + k0, sA + t * 8);
    gload_lds16(gA1 + k0, sA + 2048 + t * 8);
    gload_lds16(gB0 + k0, sB + t * 8);
    gload_lds16(gB1 + k0, sB + 2048 + t * 8);
    __syncthreads();
    bf16x8_t af[4], bfr[4];
#pragma unroll
    for (int fm = 0; fm < 4; ++fm)
      af[fm] = *(const bf16x8_t*)(sA + (wm * 64 + fm * 16 + lr) * 32 + kg * 8);
#pragma unroll
    for (int fn = 0; fn < 4; ++fn)
      bfr[fn] = *(const bf16x8_t*)(sB + (wn * 64 + fn * 16 + lr) * 32 + kg * 8);
#pragma unroll
    for (int fm = 0; fm < 4; ++fm)
#pragma unroll
      for (int fn = 0; fn < 4; ++fn)
        acc[fm][fn] = __builtin_amdgcn_mfma_f32_16x16x32_bf16(af[fm], bfr[fn], acc[fm][fn], 0, 0, 0);
    __syncthreads();
  }

  const int crow = (lane >> 4) * 4;   // C/D: col = lane&15, row = (lane>>4)*4 + r
#pragma unroll
  for (int fm = 0; fm < 4; ++fm) {
    const int mb = m0 + wm * 64 + fm * 16 + crow;
#pragma unroll
    for (int fn = 0; fn < 4; ++fn) {
      const int n = n0 + wn * 64 + fn * 16 + lr;
      if (n < N) {
#pragma unroll
        for (int r = 0; r < 4; ++r)
          C[(size_t)(mb + r) * N + n] = acc[fm][fn][r];
      }
    }
  }
}

// ---------------- embedding gather (f32, float4) --------------------------------
__global__ void embed_k(const int* __restrict__ ids, const float* __restrict__ emb,
                        float* __restrict__ res) {
  int i = blockIdx.x * 256 + threadIdx.x;      // B*L*D/4 threads
  int row = i >> 8;                            // D/4 = 256 float4 per row
  int c   = i & 255;
  int id  = ids[row];
  ((float4*)res)[i] = ((const float4*)(emb + (size_t)id * D_))[c];
}

// ---------------- fused (residual += hidden) + RMSNorm -> bf16 ------------------
template <int ADD>
__global__ __launch_bounds__(256) void addrms_k(
    const float* __restrict__ hid, float* __restrict__ res,
    const float* __restrict__ w, unsigned short* __restrict__ out)
{
  const int row = blockIdx.x;
  const int t   = threadIdx.x;
  float4 v = ((const float4*)(res + (size_t)row * D_))[t];
  if (ADD) {
    float4 h = ((const float4*)(hid + (size_t)row * D_))[t];
    v.x += h.x; v.y += h.y; v.z += h.z; v.w += h.w;
    ((float4*)(res + (size_t)row * D_))[t] = v;
  }
  float ss = v.x * v.x + v.y * v.y + v.z * v.z + v.w * v.w;
#pragma unroll
  for (int o = 1; o < 64; o <<= 1) ss += __shfl_xor(ss, o);
  __shared__ float p[4];
  if ((t & 63) == 0) p[t >> 6] = ss;
  __syncthreads();
  float tot = (p[0] + p[1]) + (p[2] + p[3]);
  float rs  = rsqrtf(tot * (1.0f / (float)D_) + 1e-5f);
  float4 wv = ((const float4*)w)[t];
  ushort4 o;
  o.x = f2bf(v.x * rs * wv.x);
  o.y = f2bf(v.y * rs * wv.y);
  o.z = f2bf(v.z * rs * wv.z);
  o.w = f2bf(v.w * rs * wv.w);
  ((ushort4*)(out + (size_t)row * D_))[t] = o;
}

// ---------------- causal depthwise conv(DC=4) + bias + silu ---------------------
__global__ __launch_bounds__(256) void conv_silu_k(
    const float* __restrict__ xz, const float* __restrict__ cw, const float* __restrict__ cb,
    float* __restrict__ xc, unsigned short* __restrict__ xcbf)
{
  int i = blockIdx.x * 256 + threadIdx.x;   // B*L*DI
  int d = i & (DI_ - 1);
  int t = (i >> 11) & (L_ - 1);
  int b = i >> 21;
  const float* xp = xz + ((size_t)(b * L_ + t)) * (2 * DI_) + d;
  const float* wp = cw + d * 4;
  float a = cb[d];
#pragma unroll
  for (int j = 0; j < 4; ++j) {
    int tt = t - 3 + j;
    if (tt >= 0) a += xp[(ptrdiff_t)(j - 3) * (2 * DI_)] * wp[j];
  }
  float sg = 1.f / (1.f + __expf(-a));
  float v  = a * sg;
  xc[i]   = v;
  xcbf[i] = f2bf(v);
}

// ---------------- softplus(dt + bias) in place ----------------------------------
__global__ void softplus_k(float* __restrict__ dt, const float* __restrict__ bias) {
  int i   = blockIdx.x * 256 + threadIdx.x;   // B*L*DI
  float v = dt[i] + bias[i & (DI_ - 1)];
  dt[i]   = (v > 20.f) ? v : log1pf(__expf(v));
}

// ---------------- selective scan: thread per (b,d,s), shfl-reduce over s --------
__global__ __launch_bounds__(256) void scan_k(
    const float* __restrict__ dt, const float* __restrict__ xc,
    const float* __restrict__ xz, const float* __restrict__ dbl,
    const float* __restrict__ alog, const float* __restrict__ dskip,
    unsigned short* __restrict__ y)
{
  int tid = blockIdx.x * 256 + threadIdx.x;   // B*DI*DS = 65536
  int s = tid & 15;
  int d = (tid >> 4) & (DI_ - 1);
  int b = tid >> 15;
  float a    = -__expf(alog[d * DS_ + s]);
  float skip = dskip[d];
  float hc   = 0.f;
  const float* dtp = dt  + (size_t)b * L_ * DI_ + d;
  const float* xp  = xc  + (size_t)b * L_ * DI_ + d;
  const float* zp  = xz  + (size_t)b * L_ * 2 * DI_ + DI_ + d;
  const float* bp  = dbl + (size_t)b * L_ * 96 + 64 + s;
  unsigned short* yp = y + (size_t)b * L_ * DI_ + d;
  for (int t = 0; t < L_; ++t) {
    float dtv = dtp[(size_t)t * DI_];
    float xv  = xp[(size_t)t * DI_];
    float Bv  = bp[(size_t)t * 96];
    float Cv  = bp[(size_t)t * 96 + 16];
    float dA  = __expf(dtv * a);
    hc = dA * hc + dtv * Bv * xv;
    float yv = hc * Cv;
    yv += __shfl_xor(yv, 1);
    yv += __shfl_xor(yv, 2);
    yv += __shfl_xor(yv, 4);
    yv += __shfl_xor(yv, 8);
    if (s == 0) {
      float zv = zp[(size_t)t * 2 * DI_];
      float sg = 1.f / (1.f + __expf(-zv));
      yp[(size_t)t * DI_] = f2bf((yv + xv * skip) * zv * sg);
    }
  }
}

// ---------------- f32 -> bf16 bulk convert (x4) ---------------------------------
__global__ void f2b_k(const float* __restrict__ in, unsigned short* __restrict__ out, int n4) {
  int i = blockIdx.x * 256 + threadIdx.x;
  if (i >= n4) return;
  float4 v = ((const float4*)in)[i];
  ushort4 o;
  o.x = f2bf(v.x); o.y = f2bf(v.y); o.z = f2bf(v.z); o.w = f2bf(v.w);
  ((ushort4*)out)[i] = o;
}

extern "C" void kernel_launch(void* const* d_in, const int* in_sizes, int n_in,
                              void* d_out, int out_size, void* d_ws, size_t ws_size,
                              hipStream_t stream)
{
  const int*   ids   = (const int*)d_in[0];
  const float* emb   = (const float*)d_in[1];
  const float* normw = (const float*)d_in[2];
  const float* inpw  = (const float*)d_in[3];
  const float* convw = (const float*)d_in[4];
  const float* convb = (const float*)d_in[5];
  const float* xpw   = (const float*)d_in[6];
  const float* dtpw  = (const float*)d_in[7];
  const float* dtpb  = (const float*)d_in[8];
  const float* alog  = (const float*)d_in[9];
  const float* dskip = (const float*)d_in[10];
  const float* opw   = (const float*)d_in[11];
  const float* normf = (const float*)d_in[12];
  float* logits = (float*)d_out;

  char* p = (char*)d_ws;
  auto alloc = [&](size_t bytes) {
    char* r = p; p += (bytes + 255) & ~(size_t)255; return r;
  };
  float*          RES   = (float*)alloc((size_t)B_ * L_ * D_ * 4);
  float*          HID   = (float*)alloc((size_t)B_ * L_ * D_ * 4);
  unsigned short* HBF   = (unsigned short*)alloc((size_t)B_ * L_ * D_ * 2);
  float*          XZ    = (float*)alloc((size_t)B_ * L_ * 2 * DI_ * 4);
  float*          XC    = (float*)alloc((size_t)B_ * L_ * DI_ * 4);
  unsigned short* XCBF  = (unsigned short*)alloc((size_t)B_ * L_ * DI_ * 2);
  float*          DBL   = (float*)alloc((size_t)B_ * L_ * 96 * 4);
  unsigned short* DBLBF = (unsigned short*)alloc((size_t)B_ * L_ * 96 * 2);
  float*          DT    = (float*)alloc((size_t)B_ * L_ * DI_ * 4);
  unsigned short* YBF   = (unsigned short*)alloc((size_t)B_ * L_ * DI_ * 2);
  unsigned short* WIN   = (unsigned short*)alloc((size_t)2 * DI_ * D_ * 2);
  unsigned short* WXP   = (unsigned short*)alloc((size_t)96 * DI_ * 2);
  unsigned short* WDT   = (unsigned short*)alloc((size_t)DI_ * DTR_ * 2);
  unsigned short* WOP   = (unsigned short*)alloc((size_t)D_ * DI_ * 2);
  unsigned short* EMBBF = (unsigned short*)alloc((size_t)V_ * D_ * 2);

  embed_k<<<(B_ * L_ * D_ / 4) / 256, 256, 0, stream>>>(ids, emb, RES);

  for (int l = 0; l < NL_; ++l) {
    f2b_k<<<(2 * DI_ * D_ / 4 + 255) / 256, 256, 0, stream>>>(
        inpw + (size_t)l * 2 * DI_ * D_, WIN, 2 * DI_ * D_ / 4);
    f2b_k<<<(96 * DI_ / 4 + 255) / 256, 256, 0, stream>>>(
        xpw + (size_t)l * 96 * DI_, WXP, 96 * DI_ / 4);
    f2b_k<<<(DI_ * DTR_ / 4 + 255) / 256, 256, 0, stream>>>(
        dtpw + (size_t)l * DI_ * DTR_, WDT, DI_ * DTR_ / 4);
    f2b_k<<<(D_ * DI_ / 4 + 255) / 256, 256, 0, stream>>>(
        opw + (size_t)l * D_ * DI_, WOP, D_ * DI_ / 4);

    if (l == 0)
      addrms_k<0><<<B_ * L_, 256, 0, stream>>>(HID, RES, normw + l * D_, HBF);
    else
      addrms_k<1><<<B_ * L_, 256, 0, stream>>>(HID, RES, normw + l * D_, HBF);

    // xz = h @ in_proj^T : M=2048 N=4096 K=1024
    gemm_bt<<<dim3(2 * DI_ / 128, B_ * L_ / 128), 256, 0, stream>>>(HBF, WIN, XZ, 2 * DI_, D_, D_);
    conv_silu_k<<<B_ * L_ * DI_ / 256, 256, 0, stream>>>(
        XZ, convw + (size_t)l * DI_ * DC_, convb + (size_t)l * DI_, XC, XCBF);
    // dbl = x @ x_proj^T : N=96 K=2048
    gemm_bt<<<dim3(1, B_ * L_ / 128), 256, 0, stream>>>(XCBF, WXP, DBL, 96, DI_, DI_);
    f2b_k<<<(B_ * L_ * 96 / 4 + 255) / 256, 256, 0, stream>>>(DBL, DBLBF, B_ * L_ * 96 / 4);
    // dt_raw = dbl[:, :64] @ dt_proj^T : N=2048 K=64, lda=96
    gemm_bt<<<dim3(DI_ / 128, B_ * L_ / 128), 256, 0, stream>>>(DBLBF, WDT, DT, DI_, DTR_, 96);
    softplus_k<<<B_ * L_ * DI_ / 256, 256, 0, stream>>>(DT, dtpb + (size_t)l * DI_);
    scan_k<<<B_ * DI_ * DS_ / 256, 256, 0, stream>>>(
        DT, XC, XZ, DBL, alog + (size_t)l * DI_ * DS_, dskip + (size_t)l * DI_, YBF);
    // hidden = y @ out_proj^T : N=1024 K=2048
    gemm_bt<<<dim3(D_ / 128, B_ * L_ / 128), 256, 0, stream>>>(YBF, WOP, HID, D_, DI_, DI_);
  }

  addrms_k<1><<<B_ * L_, 256, 0, stream>>>(HID, RES, normf, HBF);
  f2b_k<<<(V_ * D_ / 4 + 255) / 256, 256, 0, stream>>>(emb, EMBBF, V_ * D_ / 4);
  // logits = h @ emb^T : M=2048 N=50280 K=1024
  gemm_bt<<<dim3((V_ + 127) / 128, B_ * L_ / 128), 256, 0, stream>>>(HBF, EMBBF, logits, V_, D_, D_);
}